// Round 5
// baseline (238.667 us; speedup 1.0000x reference)
//
#include <hip/hip_runtime.h>

// ---------------------------------------------------------------------------
// Attention block: out = (softmax((q Wq^T+bq)(k Wk^T+bk)^T / 8) (v Wv^T+bv)) Wo^T + bo
// B=4 T=2048 C=1024 H=16 CH=64.  Internal compute bf16 MFMA + f32 accum.
// R4: attn rewritten on 32x32x16 MFMA. S^T = mfma(K,Q) -> lane owns one q-row;
//     P redistributed in-register via cvt_pk + v_permlane32_swap (no P LDS);
//     no online max (exp2 direct, safe range); O transposed via LDS epilogue.
// ---------------------------------------------------------------------------

typedef short bf8 __attribute__((ext_vector_type(8)));      // 8 bf16 (4 VGPRs)
typedef float f4 __attribute__((ext_vector_type(4)));
typedef float f16v __attribute__((ext_vector_type(16)));
typedef unsigned short u16;

#define AS1 __attribute__((address_space(1)))
#define AS3 __attribute__((address_space(3)))

__device__ __forceinline__ u16 f2b(float f) {
  unsigned u = __builtin_bit_cast(unsigned, f);
  u += 0x7FFFu + ((u >> 16) & 1u);          // RNE
  return (u16)(u >> 16);
}

__device__ __forceinline__ unsigned cvtpk(float lo, float hi) {
  unsigned r;
  asm("v_cvt_pk_bf16_f32 %0, %1, %2" : "=v"(r) : "v"(lo), "v"(hi));
  return r;
}

__device__ __forceinline__ void swap32(unsigned& a, unsigned& b) {
  asm("v_permlane32_swap_b32 %0, %1" : "+v"(a), "+v"(b));
}

// ---------------- fp32 -> bf16 convert (vectorized) ----------------
__global__ void cvt_kernel(const float* __restrict__ in, u16* __restrict__ out, int n4) {
  int i = blockIdx.x * blockDim.x + threadIdx.x;
  if (i >= n4) return;
  float4 f = ((const float4*)in)[i];
  ushort4 o;
  o.x = f2b(f.x); o.y = f2b(f.y); o.z = f2b(f.z); o.w = f2b(f.w);
  ((ushort4*)out)[i] = o;
}

// ---------------- NT GEMM: C[M,N] = A[M,K] @ B[N,K]^T + bias ----------------
// MODE 0: C fp32 row-major [M,N], bias by col.
// MODE 1: C bf16 [B,H,T,CH]: m = b*2048+t, n = h*64+ch; bias by col; scaled.
// MODE 2: A = weights (M=1024), B = tokens (N=8192); C written [B,H,CH,T]; bias by ROW.
template<int MODE>
__global__ __launch_bounds__(256, 2)
void gemm_bt(const u16* __restrict__ A, const u16* __restrict__ B,
             const float* __restrict__ bias, void* __restrict__ Cout,
             int M, int N, int K, float scale)
{
  __shared__ __align__(16) u16 aT[128 * 64];
  __shared__ __align__(16) u16 bT[128 * 64];

  const int nbn = N >> 7;
  const int bm = blockIdx.x / nbn, bn = blockIdx.x % nbn;
  const int m0 = bm << 7, n0 = bn << 7;
  const int tid = threadIdx.x, lane = tid & 63, w = tid >> 6;
  const int wm = (w >> 1) << 6, wn = (w & 1) << 6;
  const int lr = lane & 15, lg = lane >> 4;

  f4 acc[4][4] = {};

  for (int k0 = 0; k0 < K; k0 += 64) {
    __syncthreads();
    #pragma unroll
    for (int q = 0; q < 4; ++q) {
      const int c = ((w * 4 + q) << 6) + lane;
      const int row = c >> 3, kc = (c & 7) << 3;
      __builtin_amdgcn_global_load_lds(
          (const AS1 void*)(A + (size_t)(m0 + row) * K + k0 + kc),
          (AS3 void*)(aT + ((w * 4 + q) << 9)), 16, 0, 0);
      __builtin_amdgcn_global_load_lds(
          (const AS1 void*)(B + (size_t)(n0 + row) * K + k0 + kc),
          (AS3 void*)(bT + ((w * 4 + q) << 9)), 16, 0, 0);
    }
    __syncthreads();

    #pragma unroll
    for (int ks = 0; ks < 2; ++ks) {
      bf8 af[4], bfr[4];
      #pragma unroll
      for (int i = 0; i < 4; ++i) {
        af[i]  = *(const bf8*)(aT + ((wm + i * 16 + lr) << 6) + ks * 32 + lg * 8);
        bfr[i] = *(const bf8*)(bT + ((wn + i * 16 + lr) << 6) + ks * 32 + lg * 8);
      }
      __builtin_amdgcn_s_setprio(1);
      #pragma unroll
      for (int i = 0; i < 4; ++i)
        #pragma unroll
        for (int j = 0; j < 4; ++j)
          acc[i][j] = __builtin_amdgcn_mfma_f32_16x16x32_bf16(af[i], bfr[j], acc[i][j], 0, 0, 0);
      __builtin_amdgcn_s_setprio(0);
    }
  }

  if (MODE == 0) {
    float bv[4];
    #pragma unroll
    for (int j = 0; j < 4; ++j) bv[j] = bias[n0 + wn + j * 16 + lr];
    float* C = (float*)Cout;
    #pragma unroll
    for (int i = 0; i < 4; ++i)
      #pragma unroll
      for (int j = 0; j < 4; ++j) {
        const int col = n0 + wn + j * 16 + lr;
        #pragma unroll
        for (int r = 0; r < 4; ++r) {
          const int row = m0 + wm + i * 16 + lg * 4 + r;
          C[(size_t)row * N + col] = acc[i][j][r] + bv[j];
        }
      }
  } else if (MODE == 1) {
    float bv[4];
    #pragma unroll
    for (int j = 0; j < 4; ++j) bv[j] = bias[n0 + wn + j * 16 + lr];
    u16* C = (u16*)Cout;
    #pragma unroll
    for (int i = 0; i < 4; ++i)
      #pragma unroll
      for (int j = 0; j < 4; ++j) {
        const int col = n0 + wn + j * 16 + lr;
        const int h = col >> 6, ch = col & 63;
        #pragma unroll
        for (int r = 0; r < 4; ++r) {
          const int row = m0 + wm + i * 16 + lg * 4 + r;
          const int b = row >> 11, t = row & 2047;
          C[((size_t)(b * 16 + h) * 2048 + t) * 64 + ch] = f2b((acc[i][j][r] + bv[j]) * scale);
        }
      }
  } else {
    u16* C = (u16*)Cout;
    #pragma unroll
    for (int i = 0; i < 4; ++i)
      #pragma unroll
      for (int r = 0; r < 4; ++r) {
        const int nch = m0 + wm + i * 16 + lg * 4 + r;
        const float br = bias[nch];
        const int h = nch >> 6, ch = nch & 63;
        #pragma unroll
        for (int j = 0; j < 4; ++j) {
          const int tok = n0 + wn + j * 16 + lr;
          const int b = tok >> 11, t = tok & 2047;
          C[((size_t)((b * 16 + h) * 64 + ch) << 11) + t] = f2b(acc[i][j][r] + br);
        }
      }
  }
}

// ---------------- flash attention (32x32 MFMA, in-register P) ----------------
// grid 1024 (XCD-mapped: 8 bh x 16 q-tiles per XCD), 256 threads = 4 waves x 32 q.
// Q (pre-scaled by 0.125*log2e), K in [B,H,T,CH]; V^T in [B,H,CH,T]; O in [B,T,C].
__global__ __launch_bounds__(256, 4)
void attn_kernel(const u16* __restrict__ Qp, const u16* __restrict__ Kp,
                 const u16* __restrict__ VT, u16* __restrict__ Ob)
{
  __shared__ __align__(16) u16 pool[16384];     // 32 KB: kt[2][4096] | vt[2][4096]; reused as ot[128][72]
  u16* const ktb = pool;
  u16* const vtb = pool + 8192;

  const int flat = blockIdx.x;
  const int xcd = flat & 7, idx = flat >> 3;
  const int bh = (xcd << 3) + (idx >> 4);
  const int tq0 = (idx & 15) << 7;

  const int tid = threadIdx.x, lane = tid & 63, w = tid >> 6;
  const int ql = lane & 31, hi = lane >> 5;
  const size_t hoff = (size_t)bh * (2048 * 64);
  const u16* Kh = Kp + hoff;
  const u16* Vh = VT + hoff;

  // Q fragments: B-operand of 32x32x16: lane holds Q[q=ql][ch = 16ks + 8hi + j]
  bf8 qf[4];
  {
    const u16* qp_ = Qp + hoff + (size_t)(tq0 + w * 32 + ql) * 64 + hi * 8;
    #pragma unroll
    for (int ks = 0; ks < 4; ++ks) qf[ks] = *(const bf8*)(qp_ + 16 * ks);
  }

  f16v o0 = {}, o1 = {};
  float lrun = 0.f;

  // staging (same as R3): 4 global_load_lds per wave per tile
  const int c0i = (w << 7) + lane;
  const int c1i = c0i + 64;
  const int sr0 = c0i >> 3, ss0 = ((c0i & 7) ^ (sr0 & 7)) << 3;
  const int sr1 = c1i >> 3, ss1 = ((c1i & 7) ^ (sr1 & 7)) << 3;
  const int sd0 = (w << 10);
  const int sd1 = (w << 10) + 512;

  #define STAGE(buf, t0)                                                          \
    do {                                                                           \
      __builtin_amdgcn_global_load_lds((const AS1 void*)(Kh + (size_t)((t0) + sr0) * 64 + ss0), \
                                       (AS3 void*)(ktb + (buf) * 4096 + sd0), 16, 0, 0);  \
      __builtin_amdgcn_global_load_lds((const AS1 void*)(Kh + (size_t)((t0) + sr1) * 64 + ss1), \
                                       (AS3 void*)(ktb + (buf) * 4096 + sd1), 16, 0, 0);  \
      __builtin_amdgcn_global_load_lds((const AS1 void*)(Vh + (size_t)sr0 * 2048 + (t0) + ss0), \
                                       (AS3 void*)(vtb + (buf) * 4096 + sd0), 16, 0, 0);  \
      __builtin_amdgcn_global_load_lds((const AS1 void*)(Vh + (size_t)sr1 * 2048 + (t0) + ss1), \
                                       (AS3 void*)(vtb + (buf) * 4096 + sd1), 16, 0, 0);  \
    } while (0)

  STAGE(0, 0);
  __syncthreads();

  const int xq = ql & 7;      // row-XOR term (same for rows ql and 32+ql)
  int cur = 0;
  for (int t0 = 0; t0 < 2048; t0 += 64) {
    if (t0 + 64 < 2048) STAGE(cur ^ 1, t0 + 64);

    const u16* kb = ktb + cur * 4096;
    const u16* vb = vtb + cur * 4096;

    // S^T = K Q^T: s0 -> tk rows 0-31, s1 -> tk rows 32-63 (of this tile)
    f16v s0 = {}, s1 = {};
    #pragma unroll
    for (int ks = 0; ks < 4; ++ks) {
      bf8 kf0 = *(const bf8*)(kb + (ql << 6) + ((((ks << 1) + hi) ^ xq) << 3));
      bf8 kf1 = *(const bf8*)(kb + ((32 + ql) << 6) + ((((ks << 1) + hi) ^ xq) << 3));
      __builtin_amdgcn_s_setprio(1);
      s0 = __builtin_amdgcn_mfma_f32_32x32x16_bf16(kf0, qf[ks], s0, 0, 0, 0);
      s1 = __builtin_amdgcn_mfma_f32_32x32x16_bf16(kf1, qf[ks], s1, 0, 0, 0);
      __builtin_amdgcn_s_setprio(0);
    }

    // P = exp2(S) (Q pre-scaled; no max-shift needed: |s| small), pack to bf16
    unsigned wpk[16];
    float rs = 0.f;
    #pragma unroll
    for (int i = 0; i < 8; ++i) {
      float e0 = __builtin_amdgcn_exp2f(s0[2 * i]);
      float e1 = __builtin_amdgcn_exp2f(s0[2 * i + 1]);
      rs += e0 + e1;
      wpk[i] = cvtpk(e0, e1);
    }
    #pragma unroll
    for (int i = 0; i < 8; ++i) {
      float e0 = __builtin_amdgcn_exp2f(s1[2 * i]);
      float e1 = __builtin_amdgcn_exp2f(s1[2 * i + 1]);
      rs += e0 + e1;
      wpk[8 + i] = cvtpk(e0, e1);
    }
    lrun += rs;

    // redistribute P across lane halves -> PV B-fragments (P^T[k=tk][col=q])
    bf8 pf[4];
    #pragma unroll
    for (int ks = 0; ks < 4; ++ks) {
      const int base = (ks >> 1) * 8 + (ks & 1) * 4;
      swap32(wpk[base + 0], wpk[base + 2]);
      swap32(wpk[base + 1], wpk[base + 3]);
      uint4 u = make_uint4(wpk[base + 0], wpk[base + 1], wpk[base + 2], wpk[base + 3]);
      pf[ks] = __builtin_bit_cast(bf8, u);
    }

    // O^T += V^T P^T : o0 -> ch 0-31, o1 -> ch 32-63
    #pragma unroll
    for (int ks = 0; ks < 4; ++ks) {
      bf8 vf0 = *(const bf8*)(vb + (ql << 6) + ((((ks << 1) + hi) ^ xq) << 3));
      bf8 vf1 = *(const bf8*)(vb + ((32 + ql) << 6) + ((((ks << 1) + hi) ^ xq) << 3));
      __builtin_amdgcn_s_setprio(1);
      o0 = __builtin_amdgcn_mfma_f32_32x32x16_bf16(vf0, pf[ks], o0, 0, 0, 0);
      o1 = __builtin_amdgcn_mfma_f32_32x32x16_bf16(vf1, pf[ks], o1, 0, 0, 0);
      __builtin_amdgcn_s_setprio(0);
    }

    __syncthreads();
    cur ^= 1;
  }
  #undef STAGE

  // normalize: row sum = own partial + partner partial (tk halves)
  const float linv = 1.f / (lrun + __shfl_xor(lrun, 32));

  // transpose O through LDS for coalesced stores. ot[128][72] u16.
  __syncthreads();
  u16* const ot = pool;
  const int orow = w * 32 + ql;
  #pragma unroll
  for (int c = 0; c < 2; ++c) {
    const f16v& o = c ? o1 : o0;
    #pragma unroll
    for (int g = 0; g < 4; ++g) {
      // regs 4g..4g+3 -> ch = 32c + 8g + 4hi + {0..3}
      uint2 pk;
      pk.x = cvtpk(o[4 * g + 0] * linv, o[4 * g + 1] * linv);
      pk.y = cvtpk(o[4 * g + 2] * linv, o[4 * g + 3] * linv);
      *(uint2*)(ot + orow * 72 + 32 * c + 8 * g + 4 * hi) = pk;
    }
  }
  __syncthreads();

  const int b = bh >> 4, h = bh & 15;
  const int row = tid >> 1, seg = tid & 1;
  const u16* src = ot + row * 72 + seg * 32;
  u16* dst = Ob + ((size_t)(b * 2048 + tq0 + row) * 16 + h) * 64 + seg * 32;
  #pragma unroll
  for (int kk = 0; kk < 4; ++kk)
    *(uint4*)(dst + 8 * kk) = *(const uint4*)(src + 8 * kk);
}

// ---------------- host launch ----------------
extern "C" void kernel_launch(void* const* d_in, const int* in_sizes, int n_in,
                              void* d_out, int out_size, void* d_ws, size_t ws_size,
                              hipStream_t stream) {
  (void)in_sizes; (void)n_in; (void)out_size; (void)ws_size;
  const float* k_in = (const float*)d_in[0];
  const float* q_in = (const float*)d_in[1];
  const float* v_in = (const float*)d_in[2];
  const float* Wk = (const float*)d_in[3]; const float* bk = (const float*)d_in[4];
  const float* Wq = (const float*)d_in[5]; const float* bq = (const float*)d_in[6];
  const float* Wv = (const float*)d_in[7]; const float* bv = (const float*)d_in[8];
  const float* Wo = (const float*)d_in[9]; const float* bo = (const float*)d_in[10];
  float* out = (float*)d_out;

  char* ws = (char*)d_ws;
  const size_t SZ_ACT = (size_t)8192 * 1024 * 2;
  const size_t SZ_W   = (size_t)1024 * 1024 * 2;
  u16* qb  = (u16*)(ws);
  u16* kb  = (u16*)(ws + SZ_ACT);
  u16* vb  = (u16*)(ws + 2 * SZ_ACT);
  u16* Qp  = (u16*)(ws + 3 * SZ_ACT);
  u16* Kp  = (u16*)(ws + 4 * SZ_ACT);
  u16* Vt  = (u16*)(ws + 5 * SZ_ACT);               // [B,H,CH,T]
  u16* Wqb = (u16*)(ws + 6 * SZ_ACT);
  u16* Wkb = (u16*)(ws + 6 * SZ_ACT + SZ_W);
  u16* Wvb = (u16*)(ws + 6 * SZ_ACT + 2 * SZ_W);
  u16* Wob = (u16*)(ws + 6 * SZ_ACT + 3 * SZ_W);
  u16* Oc  = qb;                                    // alias: qb dead after Q proj

  const int nACT4 = 8192 * 1024 / 4;
  const int nW4   = 1024 * 1024 / 4;
  cvt_kernel<<<nACT4 / 256, 256, 0, stream>>>(q_in, qb, nACT4);
  cvt_kernel<<<nACT4 / 256, 256, 0, stream>>>(k_in, kb, nACT4);
  cvt_kernel<<<nACT4 / 256, 256, 0, stream>>>(v_in, vb, nACT4);
  cvt_kernel<<<nW4 / 256, 256, 0, stream>>>(Wq, Wqb, nW4);
  cvt_kernel<<<nW4 / 256, 256, 0, stream>>>(Wk, Wkb, nW4);
  cvt_kernel<<<nW4 / 256, 256, 0, stream>>>(Wv, Wvb, nW4);
  cvt_kernel<<<nW4 / 256, 256, 0, stream>>>(Wo, Wob, nW4);

  const float c0 = 0.125f * 1.4426950408889634f;    // softmax scale * log2(e)

  gemm_bt<1><<<512, 256, 0, stream>>>(qb, Wqb, bq, Qp, 8192, 1024, 1024, c0);
  gemm_bt<1><<<512, 256, 0, stream>>>(kb, Wkb, bk, Kp, 8192, 1024, 1024, 1.f);
  gemm_bt<2><<<512, 256, 0, stream>>>(Wvb, vb, bv, Vt, 1024, 8192, 1024, 1.f);

  attn_kernel<<<1024, 256, 0, stream>>>(Qp, Kp, Vt, Oc);

  gemm_bt<0><<<512, 256, 0, stream>>>(Oc, Wob, bo, out, 8192, 1024, 1024, 1.f);
}

// Round 6
// 223.086 us; speedup vs baseline: 1.0698x; 1.0698x over previous
//
#include <hip/hip_runtime.h>

// ---------------------------------------------------------------------------
// Attention block: out = (softmax((q Wq^T+bq)(k Wk^T+bk)^T / 8) (v Wv^T+bv)) Wo^T + bo
// B=4 T=2048 C=1024 H=16 CH=64.  Internal compute bf16 MFMA + f32 accum.
// R5: GEMM LDS XOR-swizzle (T2, kills 16-way read conflicts); fp32->bf16 cvt
//     fused into GEMM activation staging (reg-staged side); weight cvts merged;
//     XCD-chunked gemm block remap. Attn unchanged from R4.
// ---------------------------------------------------------------------------

typedef short bf8 __attribute__((ext_vector_type(8)));      // 8 bf16 (4 VGPRs)
typedef float f4 __attribute__((ext_vector_type(4)));
typedef float f16v __attribute__((ext_vector_type(16)));
typedef unsigned short u16;

#define AS1 __attribute__((address_space(1)))
#define AS3 __attribute__((address_space(3)))

__device__ __forceinline__ u16 f2b(float f) {
  unsigned u = __builtin_bit_cast(unsigned, f);
  u += 0x7FFFu + ((u >> 16) & 1u);          // RNE
  return (u16)(u >> 16);
}

__device__ __forceinline__ unsigned cvtpk(float lo, float hi) {
  unsigned r;
  asm("v_cvt_pk_bf16_f32 %0, %1, %2" : "=v"(r) : "v"(lo), "v"(hi));
  return r;
}

__device__ __forceinline__ void swap32(unsigned& a, unsigned& b) {
  asm("v_permlane32_swap_b32 %0, %1" : "+v"(a), "+v"(b));
}

// ---------------- fused weight converts (4 x 1024x1024 fp32 -> bf16) --------
// Outputs are contiguous in workspace: Wq|Wk|Wv|Wo.
__global__ void cvt4_kernel(const float* __restrict__ a, const float* __restrict__ b,
                            const float* __restrict__ c, const float* __restrict__ d,
                            u16* __restrict__ out) {
  int i = blockIdx.x * blockDim.x + threadIdx.x;     // i in [0, 4*2^18)
  const int sel = i >> 18, off = i & 0x3FFFF;
  const float* src = sel == 0 ? a : sel == 1 ? b : sel == 2 ? c : d;
  float4 f = ((const float4*)src)[off];
  ushort4 o;
  o.x = f2b(f.x); o.y = f2b(f.y); o.z = f2b(f.z); o.w = f2b(f.w);
  ((ushort4*)out)[i] = o;
}

// ---------------- NT GEMM: C[M,N] = A[M,K] @ B[N,K]^T + bias ----------------
// MODE 0: C fp32 row-major [M,N], bias by col.
// MODE 1: C bf16 [B,H,T,CH]: m=b*2048+t, n=h*64+ch; bias by col; scaled.
// MODE 2: A=weights (M=1024), B=tokens (N=8192); C written [B,H,CH,T]; bias by ROW.
// FPA/FPB: that operand is fp32 in global; converted to bf16 during staging
//          (reg-staged with swizzled ds_write). bf16 operands use
//          global_load_lds with pre-swizzled source chunks.
// LDS layout: slot (row, x) holds data chunk x^(row&7) of that row (16B chunks).
template<int MODE, int FPA, int FPB>
__global__ __launch_bounds__(256, (FPA || FPB) ? 2 : 3)
void gemm_bt(const void* __restrict__ Ap, const void* __restrict__ Bp,
             const float* __restrict__ bias, void* __restrict__ Cout,
             int M, int N, int K, float scale)
{
  __shared__ __align__(16) u16 aT[128 * 64];
  __shared__ __align__(16) u16 bT[128 * 64];

  const int nbn = N >> 7;
  // XCD-chunked remap: hw block (on XCD blockIdx%8) takes a contiguous logical range
  const int cpx = gridDim.x >> 3;
  const int bid = (blockIdx.x & 7) * cpx + (blockIdx.x >> 3);
  const int bm = bid / nbn, bn = bid % nbn;
  const int m0 = bm << 7, n0 = bn << 7;
  const int tid = threadIdx.x, lane = tid & 63, w = tid >> 6;
  const int wm = (w >> 1) << 6, wn = (w & 1) << 6;
  const int lr = lane & 15, lg = lane >> 4;

  f4 acc[4][4] = {};

  // per-thread chunk ids: c = w*256 + q*64 + lane, q = 0..3
  for (int k0 = 0; k0 < K; k0 += 64) {
    // issue fp32 loads for reg-staged side before the barrier (no LDS touch)
    float4 ta[8], tb[8];
    if (FPA) {
      const float* A32 = (const float*)Ap;
      #pragma unroll
      for (int q = 0; q < 4; ++q) {
        const int c = (w << 8) + (q << 6) + lane;
        const int row = c >> 3, col = (c & 7) << 3;
        const float* s = A32 + (size_t)(m0 + row) * K + k0 + col;
        ta[2 * q]     = *(const float4*)(s);
        ta[2 * q + 1] = *(const float4*)(s + 4);
      }
    }
    if (FPB) {
      const float* B32 = (const float*)Bp;
      #pragma unroll
      for (int q = 0; q < 4; ++q) {
        const int c = (w << 8) + (q << 6) + lane;
        const int row = c >> 3, col = (c & 7) << 3;
        const float* s = B32 + (size_t)(n0 + row) * K + k0 + col;
        tb[2 * q]     = *(const float4*)(s);
        tb[2 * q + 1] = *(const float4*)(s + 4);
      }
    }

    __syncthreads();

    if (!FPA) {
      const u16* A16 = (const u16*)Ap;
      #pragma unroll
      for (int q = 0; q < 4; ++q) {
        const int c = (w << 8) + (q << 6) + lane;
        const int row = c >> 3, sw = ((c & 7) ^ (row & 7)) << 3;
        __builtin_amdgcn_global_load_lds(
            (const AS1 void*)(A16 + (size_t)(m0 + row) * K + k0 + sw),
            (AS3 void*)(aT + (((w << 2) + q) << 9)), 16, 0, 0);
      }
    }
    if (!FPB) {
      const u16* B16 = (const u16*)Bp;
      #pragma unroll
      for (int q = 0; q < 4; ++q) {
        const int c = (w << 8) + (q << 6) + lane;
        const int row = c >> 3, sw = ((c & 7) ^ (row & 7)) << 3;
        __builtin_amdgcn_global_load_lds(
            (const AS1 void*)(B16 + (size_t)(n0 + row) * K + k0 + sw),
            (AS3 void*)(bT + (((w << 2) + q) << 9)), 16, 0, 0);
      }
    }
    if (FPA) {
      #pragma unroll
      for (int q = 0; q < 4; ++q) {
        const int c = (w << 8) + (q << 6) + lane;
        const int row = c >> 3;
        uint4 pk;
        pk.x = cvtpk(ta[2 * q].x, ta[2 * q].y);
        pk.y = cvtpk(ta[2 * q].z, ta[2 * q].w);
        pk.z = cvtpk(ta[2 * q + 1].x, ta[2 * q + 1].y);
        pk.w = cvtpk(ta[2 * q + 1].z, ta[2 * q + 1].w);
        *(uint4*)(aT + (row << 6) + (((c & 7) ^ (row & 7)) << 3)) = pk;
      }
    }
    if (FPB) {
      #pragma unroll
      for (int q = 0; q < 4; ++q) {
        const int c = (w << 8) + (q << 6) + lane;
        const int row = c >> 3;
        uint4 pk;
        pk.x = cvtpk(tb[2 * q].x, tb[2 * q].y);
        pk.y = cvtpk(tb[2 * q].z, tb[2 * q].w);
        pk.z = cvtpk(tb[2 * q + 1].x, tb[2 * q + 1].y);
        pk.w = cvtpk(tb[2 * q + 1].z, tb[2 * q + 1].w);
        *(uint4*)(bT + (row << 6) + (((c & 7) ^ (row & 7)) << 3)) = pk;
      }
    }
    __syncthreads();

    #pragma unroll
    for (int ks = 0; ks < 2; ++ks) {
      bf8 af[4], bfr[4];
      #pragma unroll
      for (int i = 0; i < 4; ++i) {
        const int ra = wm + i * 16 + lr;
        const int rb = wn + i * 16 + lr;
        af[i]  = *(const bf8*)(aT + (ra << 6) + ((((ks << 2) + lg) ^ (ra & 7)) << 3));
        bfr[i] = *(const bf8*)(bT + (rb << 6) + ((((ks << 2) + lg) ^ (rb & 7)) << 3));
      }
      __builtin_amdgcn_s_setprio(1);
      #pragma unroll
      for (int i = 0; i < 4; ++i)
        #pragma unroll
        for (int j = 0; j < 4; ++j)
          acc[i][j] = __builtin_amdgcn_mfma_f32_16x16x32_bf16(af[i], bfr[j], acc[i][j], 0, 0, 0);
      __builtin_amdgcn_s_setprio(0);
    }
  }

  if (MODE == 0) {
    float bv[4];
    #pragma unroll
    for (int j = 0; j < 4; ++j) bv[j] = bias[n0 + wn + j * 16 + lr];
    float* C = (float*)Cout;
    #pragma unroll
    for (int i = 0; i < 4; ++i)
      #pragma unroll
      for (int j = 0; j < 4; ++j) {
        const int col = n0 + wn + j * 16 + lr;
        #pragma unroll
        for (int r = 0; r < 4; ++r) {
          const int row = m0 + wm + i * 16 + lg * 4 + r;
          C[(size_t)row * N + col] = acc[i][j][r] + bv[j];
        }
      }
  } else if (MODE == 1) {
    float bv[4];
    #pragma unroll
    for (int j = 0; j < 4; ++j) bv[j] = bias[n0 + wn + j * 16 + lr];
    u16* C = (u16*)Cout;
    #pragma unroll
    for (int i = 0; i < 4; ++i)
      #pragma unroll
      for (int j = 0; j < 4; ++j) {
        const int col = n0 + wn + j * 16 + lr;
        const int h = col >> 6, ch = col & 63;
        #pragma unroll
        for (int r = 0; r < 4; ++r) {
          const int row = m0 + wm + i * 16 + lg * 4 + r;
          const int b = row >> 11, t = row & 2047;
          C[((size_t)(b * 16 + h) * 2048 + t) * 64 + ch] = f2b((acc[i][j][r] + bv[j]) * scale);
        }
      }
  } else {
    u16* C = (u16*)Cout;
    #pragma unroll
    for (int i = 0; i < 4; ++i)
      #pragma unroll
      for (int r = 0; r < 4; ++r) {
        const int nch = m0 + wm + i * 16 + lg * 4 + r;
        const float br = bias[nch];
        const int h = nch >> 6, ch = nch & 63;
        #pragma unroll
        for (int j = 0; j < 4; ++j) {
          const int tok = n0 + wn + j * 16 + lr;
          const int b = tok >> 11, t = tok & 2047;
          C[((size_t)((b * 16 + h) * 64 + ch) << 11) + t] = f2b(acc[i][j][r] + br);
        }
      }
  }
}

// ---------------- flash attention (32x32 MFMA, in-register P) ----------------
// grid 1024 (XCD-mapped: 8 bh x 16 q-tiles per XCD), 256 threads = 4 waves x 32 q.
// Q (pre-scaled by 0.125*log2e), K in [B,H,T,CH]; V^T in [B,H,CH,T]; O in [B,T,C].
__global__ __launch_bounds__(256, 4)
void attn_kernel(const u16* __restrict__ Qp, const u16* __restrict__ Kp,
                 const u16* __restrict__ VT, u16* __restrict__ Ob)
{
  __shared__ __align__(16) u16 pool[16384];     // 32 KB: kt[2][4096] | vt[2][4096]; reused as ot[128][72]
  u16* const ktb = pool;
  u16* const vtb = pool + 8192;

  const int flat = blockIdx.x;
  const int xcd = flat & 7, idx = flat >> 3;
  const int bh = (xcd << 3) + (idx >> 4);
  const int tq0 = (idx & 15) << 7;

  const int tid = threadIdx.x, lane = tid & 63, w = tid >> 6;
  const int ql = lane & 31, hi = lane >> 5;
  const size_t hoff = (size_t)bh * (2048 * 64);
  const u16* Kh = Kp + hoff;
  const u16* Vh = VT + hoff;

  bf8 qf[4];
  {
    const u16* qp_ = Qp + hoff + (size_t)(tq0 + w * 32 + ql) * 64 + hi * 8;
    #pragma unroll
    for (int ks = 0; ks < 4; ++ks) qf[ks] = *(const bf8*)(qp_ + 16 * ks);
  }

  f16v o0 = {}, o1 = {};
  float lrun = 0.f;

  const int c0i = (w << 7) + lane;
  const int c1i = c0i + 64;
  const int sr0 = c0i >> 3, ss0 = ((c0i & 7) ^ (sr0 & 7)) << 3;
  const int sr1 = c1i >> 3, ss1 = ((c1i & 7) ^ (sr1 & 7)) << 3;
  const int sd0 = (w << 10);
  const int sd1 = (w << 10) + 512;

  #define STAGE(buf, t0)                                                          \
    do {                                                                           \
      __builtin_amdgcn_global_load_lds((const AS1 void*)(Kh + (size_t)((t0) + sr0) * 64 + ss0), \
                                       (AS3 void*)(ktb + (buf) * 4096 + sd0), 16, 0, 0);  \
      __builtin_amdgcn_global_load_lds((const AS1 void*)(Kh + (size_t)((t0) + sr1) * 64 + ss1), \
                                       (AS3 void*)(ktb + (buf) * 4096 + sd1), 16, 0, 0);  \
      __builtin_amdgcn_global_load_lds((const AS1 void*)(Vh + (size_t)sr0 * 2048 + (t0) + ss0), \
                                       (AS3 void*)(vtb + (buf) * 4096 + sd0), 16, 0, 0);  \
      __builtin_amdgcn_global_load_lds((const AS1 void*)(Vh + (size_t)sr1 * 2048 + (t0) + ss1), \
                                       (AS3 void*)(vtb + (buf) * 4096 + sd1), 16, 0, 0);  \
    } while (0)

  STAGE(0, 0);
  __syncthreads();

  const int xq = ql & 7;
  int cur = 0;
  for (int t0 = 0; t0 < 2048; t0 += 64) {
    if (t0 + 64 < 2048) STAGE(cur ^ 1, t0 + 64);

    const u16* kb = ktb + cur * 4096;
    const u16* vb = vtb + cur * 4096;

    f16v s0 = {}, s1 = {};
    #pragma unroll
    for (int ks = 0; ks < 4; ++ks) {
      bf8 kf0 = *(const bf8*)(kb + (ql << 6) + ((((ks << 1) + hi) ^ xq) << 3));
      bf8 kf1 = *(const bf8*)(kb + ((32 + ql) << 6) + ((((ks << 1) + hi) ^ xq) << 3));
      __builtin_amdgcn_s_setprio(1);
      s0 = __builtin_amdgcn_mfma_f32_32x32x16_bf16(kf0, qf[ks], s0, 0, 0, 0);
      s1 = __builtin_amdgcn_mfma_f32_32x32x16_bf16(kf1, qf[ks], s1, 0, 0, 0);
      __builtin_amdgcn_s_setprio(0);
    }

    unsigned wpk[16];
    float rs = 0.f;
    #pragma unroll
    for (int i = 0; i < 8; ++i) {
      float e0 = __builtin_amdgcn_exp2f(s0[2 * i]);
      float e1 = __builtin_amdgcn_exp2f(s0[2 * i + 1]);
      rs += e0 + e1;
      wpk[i] = cvtpk(e0, e1);
    }
    #pragma unroll
    for (int i = 0; i < 8; ++i) {
      float e0 = __builtin_amdgcn_exp2f(s1[2 * i]);
      float e1 = __builtin_amdgcn_exp2f(s1[2 * i + 1]);
      rs += e0 + e1;
      wpk[8 + i] = cvtpk(e0, e1);
    }
    lrun += rs;

    bf8 pf[4];
    #pragma unroll
    for (int ks = 0; ks < 4; ++ks) {
      const int base = (ks >> 1) * 8 + (ks & 1) * 4;
      swap32(wpk[base + 0], wpk[base + 2]);
      swap32(wpk[base + 1], wpk[base + 3]);
      uint4 u = make_uint4(wpk[base + 0], wpk[base + 1], wpk[base + 2], wpk[base + 3]);
      pf[ks] = __builtin_bit_cast(bf8, u);
    }

    #pragma unroll
    for (int ks = 0; ks < 4; ++ks) {
      bf8 vf0 = *(const bf8*)(vb + (ql << 6) + ((((ks << 1) + hi) ^ xq) << 3));
      bf8 vf1 = *(const bf8*)(vb + ((32 + ql) << 6) + ((((ks << 1) + hi) ^ xq) << 3));
      __builtin_amdgcn_s_setprio(1);
      o0 = __builtin_amdgcn_mfma_f32_32x32x16_bf16(vf0, pf[ks], o0, 0, 0, 0);
      o1 = __builtin_amdgcn_mfma_f32_32x32x16_bf16(vf1, pf[ks], o1, 0, 0, 0);
      __builtin_amdgcn_s_setprio(0);
    }

    __syncthreads();
    cur ^= 1;
  }
  #undef STAGE

  const float linv = 1.f / (lrun + __shfl_xor(lrun, 32));

  __syncthreads();
  u16* const ot = pool;
  const int orow = w * 32 + ql;
  #pragma unroll
  for (int c = 0; c < 2; ++c) {
    const f16v& o = c ? o1 : o0;
    #pragma unroll
    for (int g = 0; g < 4; ++g) {
      uint2 pk;
      pk.x = cvtpk(o[4 * g + 0] * linv, o[4 * g + 1] * linv);
      pk.y = cvtpk(o[4 * g + 2] * linv, o[4 * g + 3] * linv);
      *(uint2*)(ot + orow * 72 + 32 * c + 8 * g + 4 * hi) = pk;
    }
  }
  __syncthreads();

  const int b = bh >> 4, h = bh & 15;
  const int row = tid >> 1, seg = tid & 1;
  const u16* src = ot + row * 72 + seg * 32;
  u16* dst = Ob + ((size_t)(b * 2048 + tq0 + row) * 16 + h) * 64 + seg * 32;
  #pragma unroll
  for (int kk = 0; kk < 4; ++kk)
    *(uint4*)(dst + 8 * kk) = *(const uint4*)(src + 8 * kk);
}

// ---------------- host launch ----------------
extern "C" void kernel_launch(void* const* d_in, const int* in_sizes, int n_in,
                              void* d_out, int out_size, void* d_ws, size_t ws_size,
                              hipStream_t stream) {
  (void)in_sizes; (void)n_in; (void)out_size; (void)ws_size;
  const float* k_in = (const float*)d_in[0];
  const float* q_in = (const float*)d_in[1];
  const float* v_in = (const float*)d_in[2];
  const float* Wk = (const float*)d_in[3]; const float* bk = (const float*)d_in[4];
  const float* Wq = (const float*)d_in[5]; const float* bq = (const float*)d_in[6];
  const float* Wv = (const float*)d_in[7]; const float* bv = (const float*)d_in[8];
  const float* Wo = (const float*)d_in[9]; const float* bo = (const float*)d_in[10];
  float* out = (float*)d_out;

  char* ws = (char*)d_ws;
  const size_t SZ_ACT = (size_t)8192 * 1024 * 2;   // 16 MB bf16
  const size_t SZ_W   = (size_t)1024 * 1024 * 2;   // 2 MB bf16
  u16* Oc  = (u16*)(ws);
  u16* Qp  = (u16*)(ws + 1 * SZ_ACT);
  u16* Kp  = (u16*)(ws + 2 * SZ_ACT);
  u16* Vt  = (u16*)(ws + 3 * SZ_ACT);               // [B,H,CH,T]
  u16* Wqb = (u16*)(ws + 4 * SZ_ACT);
  u16* Wkb = (u16*)(ws + 4 * SZ_ACT + SZ_W);
  u16* Wvb = (u16*)(ws + 4 * SZ_ACT + 2 * SZ_W);
  u16* Wob = (u16*)(ws + 4 * SZ_ACT + 3 * SZ_W);

  // weights: one fused convert (outputs contiguous Wq|Wk|Wv|Wo)
  cvt4_kernel<<<4096, 256, 0, stream>>>(Wq, Wk, Wv, Wo, Wqb);

  const float c0 = 0.125f * 1.4426950408889634f;    // softmax scale * log2(e)

  // projections (activation side fp32, converted in staging):
  gemm_bt<1, 1, 0><<<512, 256, 0, stream>>>(q_in, Wqb, bq, Qp, 8192, 1024, 1024, c0);
  gemm_bt<1, 1, 0><<<512, 256, 0, stream>>>(k_in, Wkb, bk, Kp, 8192, 1024, 1024, 1.f);
  gemm_bt<2, 0, 1><<<512, 256, 0, stream>>>(Wvb, v_in, bv, Vt, 1024, 8192, 1024, 1.f);

  // flash attention -> [B,T,C] bf16
  attn_kernel<<<1024, 256, 0, stream>>>(Qp, Kp, Vt, Oc);

  // output projection -> fp32 (all-bf16 operands)
  gemm_bt<0, 0, 0><<<512, 256, 0, stream>>>(Oc, Wob, bo, out, 8192, 1024, 1024, 1.f);
}